// Round 4
// baseline (2004.973 us; speedup 1.0000x reference)
//
#include <hip/hip_runtime.h>
#include <hip/hip_bf16.h>
#include <cstdint>
#include <cstddef>

// nODE: 50 Euler steps of  x <- x*(1+dt*gamma) + dt*tanh(x @ W^T + b)
// Round 4: persistent-state kernel with DECOUPLED WAVES.
//  - block owns 64 batch rows; 8 waves, wave w owns output cols [w*64,w*64+64)
//  - state fp32 in VGPRs; state-hi bf16 in padded ldsA (stride 520)
//  - W staging is WAVE-PRIVATE (4KB k-slices, double-buffered global_load_lds,
//    explicit s_waitcnt vmcnt(4)) -> NO barriers inside the K-loop
//  - only 2 __syncthreads per step (around the ldsA state rewrite)
//  - bias folded into accumulator init

#define D_DIM 512
#define BATCH_N 32768
#define NSTEPS 50

typedef __bf16 bf16x8 __attribute__((ext_vector_type(8)));
typedef float f32x4 __attribute__((ext_vector_type(4)));

typedef __attribute__((address_space(1))) const void gv_t;
typedef __attribute__((address_space(3))) void lv_t;

// s_waitcnt imm encoding (gfx9): [3:0] vmcnt lo, [6:4] expcnt, [11:8] lgkmcnt,
// [15:14] vmcnt hi. 0xF74 = vmcnt(4), others don't-care. 0xF70 = vmcnt(0).
#define WAIT_VM4() __builtin_amdgcn_s_waitcnt(0xF74)

__device__ __forceinline__ float bf16_bits_to_f(unsigned short u) {
    union { unsigned int i; float f; } c;
    c.i = ((unsigned int)u) << 16;
    return c.f;
}
__device__ __forceinline__ unsigned short f_to_bf16_bits(float f) {
    union { float f; unsigned int i; } c;
    c.f = f;
    unsigned int u = c.i;
    unsigned int r = (u + 0x7fffu + ((u >> 16) & 1u)) >> 16;  // RNE
    return (unsigned short)r;
}

__global__ __launch_bounds__(256) void f32_to_bf16_vec4(
    const float* __restrict__ src, unsigned short* __restrict__ dst, int nv) {
    int i = blockIdx.x * blockDim.x + threadIdx.x;
    if (i < nv) {
        float4 v = ((const float4*)src)[i];
        ushort4 o;
        o.x = f_to_bf16_bits(v.x);
        o.y = f_to_bf16_bits(v.y);
        o.z = f_to_bf16_bits(v.z);
        o.w = f_to_bf16_bits(v.w);
        ((ushort4*)dst)[i] = o;
    }
}

#define A_STRIDE 520   // padded: 1040 B row, 16B-aligned, bank-balanced

__global__ __launch_bounds__(512, 2) void node_persist(
    const float* __restrict__ X,              // fp32 [32768][512]
    const unsigned short* __restrict__ Wb,    // bf16 [512][512]
    const float* __restrict__ bias,           // [512]
    const float* __restrict__ gamma,          // [512]
    float* __restrict__ Fout)                 // fp32 [32768][512]
{
    __shared__ unsigned short ldsA[64 * A_STRIDE];   // 66,560 B state-hi
    __shared__ unsigned short ldsW[8 * 2 * 2048];    // 65,536 B: 8 waves x 2 bufs x 4KB

    const int tid  = threadIdx.x;
    const int lane = tid & 63;
    const int w    = tid >> 6;        // wave 0..7 -> cols [w*64, w*64+64)
    const int l16  = lane & 15;
    const int quad = lane >> 4;
    const int bm   = blockIdx.x;      // 0..511
    const float dt = 1.0f / 50.0f;

    unsigned short* myW = &ldsW[w * 4096];   // 2 bufs x 2048 elems

    // ---- W staging geometry (wave-private 64 rows x 32 k = 4KB slice) ----
    // issue i (0..3): row_local = i*16 + (lane>>2), slot j = lane&3,
    // XOR: global k-chunk kc = j ^ (row_local & 3)  [= j ^ ((lane>>2)&3)]
    const int rl = lane >> 2;
    const int kc = (lane & 3) ^ (rl & 3);
    int gofs[4];
#pragma unroll
    for (int i = 0; i < 4; ++i)
        gofs[i] = (w * 64 + i * 16 + rl) * D_DIM + kc * 8;   // + sl*32 per slice

    // B-frag read offsets (within my 2048-elem buf): row t*16+l16, chunk quad^XOR
    int boff[4];
#pragma unroll
    for (int t = 0; t < 4; ++t)
        boff[t] = (t * 16 + l16) * 32 + (quad ^ (l16 & 3)) * 8;

    // ---- per-lane column constants ----
    const int c0 = w * 64 + l16;
    float bc[4], g1[4];
#pragma unroll
    for (int tn = 0; tn < 4; ++tn) {
        bc[tn] = bias[c0 + tn * 16];
        g1[tn] = 1.0f + dt * gamma[c0 + tn * 16];
    }

    // ---- load initial state (fp32, C-layout aligned) ----
    const int r0 = quad * 4;
    float s[4][4][4];
#pragma unroll
    for (int tm = 0; tm < 4; ++tm)
#pragma unroll
        for (int tn = 0; tn < 4; ++tn)
#pragma unroll
            for (int r = 0; r < 4; ++r)
                s[tm][tn][r] =
                    X[(size_t)(bm * 64 + r0 + tm * 16 + r) * D_DIM + c0 + tn * 16];

    // ---- write initial state-hi into padded ldsA ----
#pragma unroll
    for (int tm = 0; tm < 4; ++tm)
#pragma unroll
        for (int tn = 0; tn < 4; ++tn)
#pragma unroll
            for (int r = 0; r < 4; ++r)
                ldsA[(r0 + tm * 16 + r) * A_STRIDE + c0 + tn * 16] =
                    f_to_bf16_bits(s[tm][tn][r]);

    // ---- prime W double-buffer: slices 0 and 1 ----
#pragma unroll
    for (int i = 0; i < 4; ++i)
        __builtin_amdgcn_global_load_lds(
            (gv_t*)(Wb + gofs[i]), (lv_t*)(myW + i * 512), 16, 0, 0);
#pragma unroll
    for (int i = 0; i < 4; ++i)
        __builtin_amdgcn_global_load_lds(
            (gv_t*)(Wb + gofs[i] + 32), (lv_t*)(myW + 2048 + i * 512), 16, 0, 0);

    __syncthreads();   // ldsA ready for all waves; primes drained too

    const f32x4 zero = {0.f, 0.f, 0.f, 0.f};
    for (int step = 0; step < NSTEPS; ++step) {
        f32x4 acc[4][4];
#pragma unroll
        for (int tm = 0; tm < 4; ++tm)
#pragma unroll
            for (int tn = 0; tn < 4; ++tn) {
                f32x4 b4 = {bc[tn], bc[tn], bc[tn], bc[tn]};
                acc[tm][tn] = b4;   // bias folded into acc init
            }

        for (int kb = 0; kb < 16; ++kb) {
            WAIT_VM4();   // slice kb landed (<=4 outstanding: slice kb+1's loads)

            bf16x8 af[4], bf[4];
#pragma unroll
            for (int t = 0; t < 4; ++t)
                af[t] = *reinterpret_cast<const bf16x8*>(
                    &ldsA[(t * 16 + l16) * A_STRIDE + kb * 32 + quad * 8]);
#pragma unroll
            for (int t = 0; t < 4; ++t)
                bf[t] = *reinterpret_cast<const bf16x8*>(
                    &myW[(kb & 1) * 2048 + boff[t]]);

#pragma unroll
            for (int tm = 0; tm < 4; ++tm)
#pragma unroll
                for (int tn = 0; tn < 4; ++tn)
                    acc[tm][tn] = __builtin_amdgcn_mfma_f32_16x16x32_bf16(
                        af[tm], bf[tn], acc[tm][tn], 0, 0, 0);

            // Prefetch slice kb+2 into the buffer just consumed.
            // (kb+2)&15 wraps to next step's slices 0,1 during kb=14,15 --
            // W is step-invariant so the wrap is exactly what we need.
            const int nsl = (kb + 2) & 15;
#pragma unroll
            for (int i = 0; i < 4; ++i)
                __builtin_amdgcn_global_load_lds(
                    (gv_t*)(Wb + gofs[i] + nsl * 32),
                    (lv_t*)(myW + (kb & 1) * 2048 + i * 512), 16, 0, 0);
        }

        // ---- Euler update in registers ----
#pragma unroll
        for (int tm = 0; tm < 4; ++tm)
#pragma unroll
            for (int tn = 0; tn < 4; ++tn)
#pragma unroll
                for (int r = 0; r < 4; ++r) {
                    float y = acc[tm][tn][r];             // already includes bias
                    float e = __expf(2.0f * y);
                    float th = 1.0f - 2.0f * __builtin_amdgcn_rcpf(e + 1.0f);
                    s[tm][tn][r] = s[tm][tn][r] * g1[tn] + dt * th;
                }

        if (step == NSTEPS - 1) break;

        __syncthreads();   // all waves done reading ldsA for this step
#pragma unroll
        for (int tm = 0; tm < 4; ++tm)
#pragma unroll
            for (int tn = 0; tn < 4; ++tn)
#pragma unroll
                for (int r = 0; r < 4; ++r)
                    ldsA[(r0 + tm * 16 + r) * A_STRIDE + c0 + tn * 16] =
                        f_to_bf16_bits(s[tm][tn][r]);
        __syncthreads();   // new state-hi visible to all waves
    }

    // ---- final fp32 store ----
#pragma unroll
    for (int tm = 0; tm < 4; ++tm)
#pragma unroll
        for (int tn = 0; tn < 4; ++tn)
#pragma unroll
            for (int r = 0; r < 4; ++r)
                Fout[(size_t)(bm * 64 + r0 + tm * 16 + r) * D_DIM + c0 + tn * 16] =
                    s[tm][tn][r];
}

extern "C" void kernel_launch(void* const* d_in, const int* in_sizes, int n_in,
                              void* d_out, int out_size, void* d_ws, size_t ws_size,
                              hipStream_t stream) {
    const float* x  = (const float*)d_in[0];   // [32768][512]
    const float* W  = (const float*)d_in[1];   // [512][512]
    const float* bi = (const float*)d_in[2];   // [512]
    const float* ga = (const float*)d_in[3];   // [512]

    unsigned short* Wb = (unsigned short*)d_ws;   // 512 KB

    f32_to_bf16_vec4<<<256, 256, 0, stream>>>(W, Wb, 262144 / 4);
    node_persist<<<dim3(512), dim3(512), 0, stream>>>(
        x, Wb, bi, ga, (float*)d_out);
}

// Round 5
// 1538.898 us; speedup vs baseline: 1.3029x; 1.3029x over previous
//
#include <hip/hip_runtime.h>
#include <hip/hip_bf16.h>
#include <cstdint>
#include <cstddef>

// nODE: 50 Euler steps of  x <- x*(1+dt*gamma) + dt*tanh(x @ W^T + b)
// Round 5:
//  - launch_bounds(512,2): 256-VGPR budget, NO SPILL (R4's 2.16GB fetch was
//    scratch thrash evicting W from L2)
//  - B (W) fragments loaded DIRECT global->VGPR (L2-hot), register
//    double-buffered; no ldsW, no B ds_reads -> LDS pipe ~halved
//  - W row-permuted at setup (sigma(i)=4*(i&15)+(i>>4)) so each lane's 4
//    output cols are adjacent: epilogue = 16x ds_write_b64 (bank-optimal),
//    X/out/bias/gamma accesses = float4
//  - state fp32 in VGPRs; state-hi bf16 in ldsA (stride 520, bank-uniform)

#define D_DIM 512
#define BATCH_N 32768
#define NSTEPS 50
#define A_STRIDE 520   // elems; row = 1040 B (16B-aligned, bank-uniform reads)

typedef __bf16 bf16x8 __attribute__((ext_vector_type(8)));
typedef float f32x4 __attribute__((ext_vector_type(4)));

__device__ __forceinline__ float bf16_bits_to_f(unsigned short u) {
    union { unsigned int i; float f; } c;
    c.i = ((unsigned int)u) << 16;
    return c.f;
}
__device__ __forceinline__ unsigned short f_to_bf16_bits(float f) {
    union { float f; unsigned int i; } c;
    c.f = f;
    unsigned int u = c.i;
    unsigned int r = (u + 0x7fffu + ((u >> 16) & 1u)) >> 16;  // RNE
    return (unsigned short)r;
}

// Build row-permuted bf16 W: Wb[w*64+i][k] = W[w*64 + sigma(i)][k],
// sigma(i) = 4*(i&15) + (i>>4).
__global__ __launch_bounds__(256) void build_wperm(
    const float* __restrict__ W, unsigned short* __restrict__ Wb) {
    int e4 = blockIdx.x * 256 + threadIdx.x;   // 0..65535 (512*128 float4)
    int k4   = e4 & 127;
    int orow = e4 >> 7;
    int i    = orow & 63;
    int srow = (orow & ~63) | (4 * (i & 15) + (i >> 4));
    float4 v = ((const float4*)W)[srow * 128 + k4];
    ushort4 o;
    o.x = f_to_bf16_bits(v.x);
    o.y = f_to_bf16_bits(v.y);
    o.z = f_to_bf16_bits(v.z);
    o.w = f_to_bf16_bits(v.w);
    ((ushort4*)Wb)[orow * 128 + k4] = o;
}

__global__ __launch_bounds__(512, 2) void node_persist(
    const float* __restrict__ X,              // fp32 [32768][512]
    const unsigned short* __restrict__ Wb,    // bf16 row-permuted [512][512]
    const float* __restrict__ bias,           // [512]
    const float* __restrict__ gamma,          // [512]
    float* __restrict__ Fout)                 // fp32 [32768][512]
{
    __shared__ unsigned short ldsA[64 * A_STRIDE];   // 66,560 B state-hi

    const int tid  = threadIdx.x;
    const int lane = tid & 63;
    const int w    = tid >> 6;        // wave 0..7 -> col strip [w*64, w*64+64)
    const int l16  = lane & 15;
    const int quad = lane >> 4;
    const int bm   = blockIdx.x;      // 0..511, rows [bm*64, bm*64+64)
    const float dt = 1.0f / 50.0f;

    // Lane's 4 TRUE output cols: ctrue0..ctrue0+3 (thanks to W row-perm).
    // acc[tm][tn] holds the value for true col ctrue0 + tn.
    const int ctrue0 = w * 64 + 4 * l16;

    // B-fragment global base pointers (per row-tile t). k offset = slice*32.
    const unsigned short* bp[4];
#pragma unroll
    for (int t = 0; t < 4; ++t)
        bp[t] = Wb + (size_t)(w * 64 + t * 16 + l16) * D_DIM + quad * 8;

    // Column constants (float4).
    float bc_[4], g1_[4];
    {
        float4 b4 = *(const float4*)&bias[ctrue0];
        float4 g4 = *(const float4*)&gamma[ctrue0];
        bc_[0] = b4.x; bc_[1] = b4.y; bc_[2] = b4.z; bc_[3] = b4.w;
        g1_[0] = 1.0f + dt * g4.x; g1_[1] = 1.0f + dt * g4.y;
        g1_[2] = 1.0f + dt * g4.z; g1_[3] = 1.0f + dt * g4.w;
    }

    // Initial state: float4 loads; s[tm][tn][r] = state of (row, ctrue0+tn).
    const int r0 = quad * 4;
    float s[4][4][4];
#pragma unroll
    for (int tm = 0; tm < 4; ++tm)
#pragma unroll
        for (int r = 0; r < 4; ++r) {
            float4 v = *(const float4*)
                &X[(size_t)(bm * 64 + r0 + tm * 16 + r) * D_DIM + ctrue0];
            s[tm][0][r] = v.x; s[tm][1][r] = v.y;
            s[tm][2][r] = v.z; s[tm][3][r] = v.w;
        }

    // Initial state-hi into ldsA (b64 writes, bank-uniform).
#pragma unroll
    for (int tm = 0; tm < 4; ++tm)
#pragma unroll
        for (int r = 0; r < 4; ++r) {
            ushort4 h;
            h.x = f_to_bf16_bits(s[tm][0][r]);
            h.y = f_to_bf16_bits(s[tm][1][r]);
            h.z = f_to_bf16_bits(s[tm][2][r]);
            h.w = f_to_bf16_bits(s[tm][3][r]);
            *(ushort4*)&ldsA[(r0 + tm * 16 + r) * A_STRIDE + ctrue0] = h;
        }

    // Prime B register double-buffer with slice 0.
    bf16x8 bf0[4], bf1[4];
#pragma unroll
    for (int t = 0; t < 4; ++t)
        bf0[t] = *reinterpret_cast<const bf16x8*>(bp[t]);

    __syncthreads();   // ldsA fully written

    for (int step = 0; step < NSTEPS; ++step) {
        f32x4 acc[4][4];
#pragma unroll
        for (int tm = 0; tm < 4; ++tm)
#pragma unroll
            for (int tn = 0; tn < 4; ++tn) {
                f32x4 b4 = {bc_[tn], bc_[tn], bc_[tn], bc_[tn]};
                acc[tm][tn] = b4;   // bias folded into acc init
            }

#pragma unroll
        for (int kb2 = 0; kb2 < 8; ++kb2) {
            const int kb = kb2 * 2;
            // Prefetch slice kb+1 into bf1 (direct global->VGPR, L2-hot).
#pragma unroll
            for (int t = 0; t < 4; ++t)
                bf1[t] = *reinterpret_cast<const bf16x8*>(
                    bp[t] + ((kb + 1) & 15) * 32);
            {
                bf16x8 af[4];
#pragma unroll
                for (int t = 0; t < 4; ++t)
                    af[t] = *reinterpret_cast<const bf16x8*>(
                        &ldsA[(t * 16 + l16) * A_STRIDE + kb * 32 + quad * 8]);
#pragma unroll
                for (int tm = 0; tm < 4; ++tm)
#pragma unroll
                    for (int tn = 0; tn < 4; ++tn)
                        acc[tm][tn] = __builtin_amdgcn_mfma_f32_16x16x32_bf16(
                            af[tm], bf0[tn], acc[tm][tn], 0, 0, 0);
            }
            // Prefetch slice kb+2 (wraps to 0 -> ready for next step) into bf0.
#pragma unroll
            for (int t = 0; t < 4; ++t)
                bf0[t] = *reinterpret_cast<const bf16x8*>(
                    bp[t] + ((kb + 2) & 15) * 32);
            {
                bf16x8 af[4];
#pragma unroll
                for (int t = 0; t < 4; ++t)
                    af[t] = *reinterpret_cast<const bf16x8*>(
                        &ldsA[(t * 16 + l16) * A_STRIDE + (kb + 1) * 32 + quad * 8]);
#pragma unroll
                for (int tm = 0; tm < 4; ++tm)
#pragma unroll
                    for (int tn = 0; tn < 4; ++tn)
                        acc[tm][tn] = __builtin_amdgcn_mfma_f32_16x16x32_bf16(
                            af[tm], bf1[tn], acc[tm][tn], 0, 0, 0);
            }
        }

        // Euler update in registers.
#pragma unroll
        for (int tm = 0; tm < 4; ++tm)
#pragma unroll
            for (int tn = 0; tn < 4; ++tn)
#pragma unroll
                for (int r = 0; r < 4; ++r) {
                    float y = acc[tm][tn][r];             // includes bias
                    float e = __expf(2.0f * y);
                    float th = 1.0f - 2.0f * __builtin_amdgcn_rcpf(e + 1.0f);
                    s[tm][tn][r] = s[tm][tn][r] * g1_[tn] + dt * th;
                }

        if (step == NSTEPS - 1) break;

        __syncthreads();   // all waves done reading ldsA
#pragma unroll
        for (int tm = 0; tm < 4; ++tm)
#pragma unroll
            for (int r = 0; r < 4; ++r) {
                ushort4 h;
                h.x = f_to_bf16_bits(s[tm][0][r]);
                h.y = f_to_bf16_bits(s[tm][1][r]);
                h.z = f_to_bf16_bits(s[tm][2][r]);
                h.w = f_to_bf16_bits(s[tm][3][r]);
                *(ushort4*)&ldsA[(r0 + tm * 16 + r) * A_STRIDE + ctrue0] = h;
            }
        __syncthreads();   // new state-hi visible
    }

    // Final fp32 store (float4, fully coalesced).
#pragma unroll
    for (int tm = 0; tm < 4; ++tm)
#pragma unroll
        for (int r = 0; r < 4; ++r) {
            float4 v;
            v.x = s[tm][0][r]; v.y = s[tm][1][r];
            v.z = s[tm][2][r]; v.w = s[tm][3][r];
            *(float4*)&Fout[(size_t)(bm * 64 + r0 + tm * 16 + r) * D_DIM + ctrue0] = v;
        }
}

extern "C" void kernel_launch(void* const* d_in, const int* in_sizes, int n_in,
                              void* d_out, int out_size, void* d_ws, size_t ws_size,
                              hipStream_t stream) {
    const float* x  = (const float*)d_in[0];   // [32768][512]
    const float* W  = (const float*)d_in[1];   // [512][512]
    const float* bi = (const float*)d_in[2];   // [512]
    const float* ga = (const float*)d_in[3];   // [512]

    unsigned short* Wb = (unsigned short*)d_ws;   // 512 KB row-permuted bf16 W

    build_wperm<<<256, 256, 0, stream>>>(W, Wb);
    node_persist<<<dim3(512), dim3(512), 0, stream>>>(
        x, Wb, bi, ga, (float*)d_out);
}